// Round 19
// baseline (2399600.586 us; speedup 1.0000x reference)
//
#include <hip/hip_runtime.h>

// LSTM H=512, B=256, T=256, D_IN=10, C=10. fp32 in/out.
// R19 = R18 + shadow-prefetch: polls AND stageA loads for step t+1 issue in
// step t's storeB/S6 window. All waves poll (lanes 0-31 flagA, 32-63 flagB);
// each wave then issues its stageA(t+1) loads; S6 is a RAW s_barrier with
// manual s_waitcnt vmcnt(8) so the 8 prefetch loads stay in flight across the
// barrier (storeB is provably drained: poll loads force its ack, and the
// manual vmcnt(8) guarantees it compiler-independently). S0/S1 gone: 5
// barriers/step (was 7). flagA still posts after S5's full drain; panel WAR
// still fenced by S5. Numerics/layout/fabric identical to R18.

#define Hdim 512
#define Bdim 256
#define Tdim 256
#define Kpad 544          // 512 (h) + 32 (x: 10 real + 22 zero)
#define LROW 552          // weight LDS row stride (shorts)
#define PROW 520          // panel LDS col stride (shorts)
#define LDS_BYTES ((64 * LROW * 2 + 16 * PROW + 512) * 2)   // 158,976 B -> 1 WG/CU

typedef __bf16 bf16x8 __attribute__((ext_vector_type(8)));
typedef float f32x4 __attribute__((ext_vector_type(4)));
typedef unsigned long long u64;

__device__ __forceinline__ unsigned short f2bf(float f) {
    union { float f; unsigned u; } x; x.f = f;
    unsigned r = x.u + 0x7FFFu + ((x.u >> 16) & 1u);
    return (unsigned short)(r >> 16);
}
__device__ __forceinline__ float bf2f(unsigned short h) {
    union { unsigned u; float f; } x; x.u = ((unsigned)h) << 16;
    return x.f;
}
__device__ __forceinline__ bf16x8 ld8(const unsigned short* p) {
    return *reinterpret_cast<const bf16x8*>(p);
}
__device__ __forceinline__ u64 ldA(const u64* p) {   // coherent 8B load (L3)
    return __hip_atomic_load(p, __ATOMIC_RELAXED, __HIP_MEMORY_SCOPE_AGENT);
}
// write-through 4B store (agent scope -> lands at coherence point)
__device__ __forceinline__ void stH32(unsigned* p, unsigned v) {
    __hip_atomic_store(p, v, __ATOMIC_RELAXED, __HIP_MEMORY_SCOPE_AGENT);
}
__device__ __forceinline__ f32x4 mfma16(bf16x8 a, bf16x8 b, f32x4 c) {
    return __builtin_amdgcn_mfma_f32_16x16x32_bf16(a, b, c, 0, 0, 0);
}
__device__ __forceinline__ bf16x8 pack2(u64 a, u64 b) {
    union { u64 q[2]; bf16x8 v; } u; u.q[0] = a; u.q[1] = b; return u.v;
}
__device__ __forceinline__ float sigm(float x) { return 1.f / (1.f + __expf(-x)); }
__device__ __forceinline__ float tanh_fast(float x) {
    return 2.f / (1.f + __expf(-2.f * x)) - 1.f;
}
// both-flag poll: every wave; lanes 0-31 watch flagA lines, 32-63 flagB lines
__device__ __forceinline__ void pollBoth(const unsigned* pollpA, const unsigned* pollpB,
                                         unsigned tgt, int lane) {
    const unsigned* p = (lane < 32) ? pollpA : pollpB;
    unsigned v = __hip_atomic_load(p, __ATOMIC_RELAXED, __HIP_MEMORY_SCOPE_AGENT);
    bool ok = (v >= tgt);
    int guard = 1 << 16;   // bounded: pathological case -> no hang
    while (!ok && --guard) {
        __builtin_amdgcn_s_sleep(1);
        v = __hip_atomic_load(p, __ATOMIC_RELAXED, __HIP_MEMORY_SCOPE_AGENT);
        ok = (v >= tgt);
    }
}

// ---------- prep: stacked gate weights -> bf16 hi/lo, row = 4*i + gate ----------
__global__ void k_prep_w(const float* __restrict__ w_gh, const float* __restrict__ w_ih,
                         const float* __restrict__ w_fh, const float* __restrict__ w_oh,
                         const float* __restrict__ w_gx, const float* __restrict__ w_ix,
                         const float* __restrict__ w_fx, const float* __restrict__ w_ox,
                         unsigned short* __restrict__ Whi, unsigned short* __restrict__ Wlo) {
    int idx = blockIdx.x * 256 + threadIdx.x;
    if (idx >= 2048 * Kpad) return;
    int rw = idx / Kpad;
    int k  = idx % Kpad;
    int gate = rw & 3;
    int i = rw >> 2;
    float v = 0.f;
    if (k < 512) {
        const float* wh = (gate == 0) ? w_gh : (gate == 1) ? w_ih : (gate == 2) ? w_fh : w_oh;
        v = wh[i * 512 + k];
    } else if (k < 522) {
        const float* wx = (gate == 0) ? w_gx : (gate == 1) ? w_ix : (gate == 2) ? w_fx : w_ox;
        v = wx[i * 10 + (k - 512)];
    }
    unsigned short hi = f2bf(v);
    unsigned short lo = f2bf(v - bf2f(hi));
    Whi[idx] = hi;
    Wlo[idx] = lo;
}

// ---------- prep: x -> Xhi/Xlo [t][b][32] ----------
__global__ void k_prep_x(const float* __restrict__ x,
                         unsigned short* __restrict__ Xhi, unsigned short* __restrict__ Xlo) {
    int idx = blockIdx.x * 256 + threadIdx.x;
    if (idx >= Tdim * Bdim * 32) return;
    int j = idx & 31;
    int b = (idx >> 5) & 255;
    int t = idx >> 13;
    float v = 0.f;
    if (j < 10) v = x[(b * Tdim + t) * 10 + j];
    unsigned short hi = f2bf(v);
    unsigned short lo = f2bf(v - bf2f(hi));
    Xhi[idx] = hi;
    Xlo[idx] = lo;
}

__global__ void k_zero(float* __restrict__ p) {
    p[blockIdx.x * 256 + threadIdx.x] = 0.f;
}

// ---------- persistent LSTM ----------
// 256 WGs x 256 thr. WG: 64 stacked rows x 32 cols. Wave w: rows w*16..+15.
// h layout: Hc[((ct*32+rg)*32 + col_local)*16 + r16] -> 1KB/WG contiguous.
__global__ __launch_bounds__(256, 1) void k_persist(
    const unsigned short* __restrict__ Whi, const unsigned short* __restrict__ Wlo,
    const unsigned short* __restrict__ Xhi, const unsigned short* __restrict__ Xlo,
    unsigned short* H0c, unsigned short* H1c,
    float* __restrict__ Hf32,
    const float* __restrict__ bg, const float* __restrict__ bi,
    const float* __restrict__ bf_, const float* __restrict__ bo,
    unsigned* flags) {
    extern __shared__ unsigned short lds[];
    unsigned short* Lhi = lds;                       // [64][LROW]
    unsigned short* Llo = lds + 64 * LROW;           // [64][LROW]
    unsigned short* Pp  = lds + 64 * LROW * 2;       // [16][PROW] panel
    unsigned short* Ho  = Pp + 16 * PROW;            // [32][16] h-out bounce

    const int bid = blockIdx.x;
    const int rg  = bid >> 3;                  // row-group id (0..31)
    const int m0  = rg * 64;                   // stacked-row tile base
    const int ct  = bid & 7;                   // column-group id
    const int bn0 = ct * 32;
    const int tid = threadIdx.x;
    const int lane = tid & 63;
    const int w  = tid >> 6;                   // wave id: rows w*16..w*16+15
    const int lr = lane & 15, q = lane >> 4;

    // flags: flagsA = flags[0..4095], flagsB = flags[4096..8191] (uints)
    unsigned* flagsA = flags;
    unsigned* flagsB = flags + 4096;
    unsigned* myflagA = flagsA + (((ct << 5) + rg) << 4);
    unsigned* myflagB = flagsB + (((ct << 5) + rg) << 4);
    const unsigned* pollpA = flagsA + (((ct << 5) + (lane & 31)) << 4);
    const unsigned* pollpB = flagsB + (((ct << 5) + (lane & 31)) << 4);

    // panel staging role: thread (cl = tid>>4, e = tid&15)
    const int cl = tid >> 4;
    const int e  = tid & 15;

    // one-time weight staging global -> LDS
    for (int it = tid; it < 64 * 68; it += 256) {
        int r = it / 68, c8 = (it % 68) * 8;
        *(bf16x8*)&Lhi[r * LROW + c8] = ld8(Whi + (size_t)(m0 + r) * Kpad + c8);
        *(bf16x8*)&Llo[r * LROW + c8] = ld8(Wlo + (size_t)(m0 + r) * Kpad + c8);
    }
    __syncthreads();

    const int kq = q * 8;
    const int col0 = bn0 + lr;                 // acc0 cell column (phase A)
    const int col1 = col0 + 16;                // acc1 cell column (phase B)
    const int i0 = rg * 16 + w * 4 + q;        // h-row of both cells
    const int r16 = w * 4 + q;                 // row%16

    float c0 = 0.f, c1 = 0.f;
    const f32x4 binit = { bg[i0], bi[i0], bf_[i0], bo[i0] };

    const unsigned short* Ah = &Lhi[(w * 16 + lr) * LROW + kq];
    const unsigned short* Al = &Llo[(w * 16 + lr) * LROW + kq];
    const unsigned short* Bl = &Pp[lr * PROW + kq];
    unsigned short* Pd0 = &Pp[cl * PROW + e * 16];        // rows of rg=e
    unsigned short* Pd1 = &Pp[cl * PROW + e * 16 + 256];  // rows of rg=e+16

    // global h block base (compact layout)
    const size_t myblk = ((size_t)ct * 32 + rg) * 512;    // this WG's 1KB block

    // source offsets for staging (within an Hc buffer)
    const size_t offA0 = (((size_t)ct * 32 + e) * 32 + cl) * 16;
    const size_t offA1 = (((size_t)ct * 32 + e + 16) * 32 + cl) * 16;
    const size_t offB0 = (((size_t)ct * 32 + e) * 32 + 16 + cl) * 16;
    const size_t offB1 = (((size_t)ct * 32 + e + 16) * 32 + 16 + cl) * 16;

    // ---- prologue: stageA(0) prefetch (H0c zeroed; gen-0 gates trivially true)
    u64 a0[4], a1[4];
    {
        const u64* s0 = (const u64*)(H0c + offA0);
        const u64* s1 = (const u64*)(H0c + offA1);
#pragma unroll
        for (int v = 0; v < 4; ++v) a0[v] = ldA(s0 + v);
#pragma unroll
        for (int v = 0; v < 4; ++v) a1[v] = ldA(s1 + v);
    }

    for (int t = 0; t < Tdim; ++t) {
        const unsigned short* Rh = (t & 1) ? H1c : H0c;   // holds h(t-1)
        unsigned short* Whc = (t & 1) ? H0c : H1c;        // receives h(t)

        // ---- 1. write panel A from prefetched regs ----
        *(bf16x8*)(Pd0)     = pack2(a0[0], a0[1]);
        *(bf16x8*)(Pd0 + 8) = pack2(a0[2], a0[3]);
        *(bf16x8*)(Pd1)     = pack2(a1[0], a1[1]);
        *(bf16x8*)(Pd1 + 8) = pack2(a1[2], a1[3]);
        __syncthreads();                       // S2: panel A ready

        // ---- 2. stageB(t) loads (flagB(t) verified in prev shadow) + x ----
        u64 b0[4], b1[4];
        {
            const u64* s0 = (const u64*)(Rh + offB0);
            const u64* s1 = (const u64*)(Rh + offB1);
#pragma unroll
            for (int v = 0; v < 4; ++v) b0[v] = ldA(s0 + v);
#pragma unroll
            for (int v = 0; v < 4; ++v) b1[v] = ldA(s1 + v);
        }
        const unsigned short* xb  = Xhi + ((size_t)t * Bdim) * 32;
        const unsigned short* xbl = Xlo + ((size_t)t * Bdim) * 32;
        bf16x8 xh0 = ld8(xb + col0 * 32 + kq), xl0 = ld8(xbl + col0 * 32 + kq);
        bf16x8 xh1 = ld8(xb + col1 * 32 + kq), xl1 = ld8(xbl + col1 * 32 + kq);

        // ---- 3. MFMA phase A (cols 0-15) -> acc0 ----
        f32x4 acc0 = binit, acc1 = binit;
#pragma unroll
        for (int kb = 0; kb < 16; ++kb) {
            const int k = kb * 32;
            bf16x8 ah = ld8(Ah + k), al = ld8(Al + k);
            bf16x8 bh = ld8(Bl + k);
            acc0 = mfma16(ah, bh, acc0);
            acc0 = mfma16(al, bh, acc0);
        }
        {   // x tail acc0
            bf16x8 ah = ld8(Ah + 512), al = ld8(Al + 512);
            acc0 = mfma16(ah, xh0, acc0);
            acc0 = mfma16(ah, xl0, acc0);
            acc0 = mfma16(al, xh0, acc0);
        }
        {   // epilogue A: cell (i0, col0) -> Ho bytes [0,512)
            float g = tanh_fast(acc0[0]), ii = sigm(acc0[1]);
            float f = sigm(acc0[2]),      o  = sigm(acc0[3]);
            c0 = g * ii + c0 * f;
            float h = tanh_fast(c0) * o;
            Ho[lr * 16 + r16] = f2bf(h);
            if (t == Tdim - 1) Hf32[(size_t)col0 * Hdim + i0] = h;
        }
        __syncthreads();                       // S3: panel A consumed + Ho-A done

        // ---- 4. write panel B (stageB data) ----
        *(bf16x8*)(Pd0)     = pack2(b0[0], b0[1]);
        *(bf16x8*)(Pd0 + 8) = pack2(b0[2], b0[3]);
        *(bf16x8*)(Pd1)     = pack2(b1[0], b1[1]);
        *(bf16x8*)(Pd1 + 8) = pack2(b1[2], b1[3]);
        __syncthreads();                       // S4: panel B ready

        // ---- 5. storeA (coalesced, bytes 0-511) overlapped with MFMA-B ----
        if (tid < 128)
            stH32((unsigned*)(Whc + myblk) + tid, *(const unsigned*)&Ho[tid * 2]);

        // ---- 6. MFMA phase B (cols 16-31) -> acc1 ----
#pragma unroll
        for (int kb = 0; kb < 16; ++kb) {
            const int k = kb * 32;
            bf16x8 ah = ld8(Ah + k), al = ld8(Al + k);
            bf16x8 bh = ld8(Bl + k);
            acc1 = mfma16(ah, bh, acc1);
            acc1 = mfma16(al, bh, acc1);
        }
        {   // x tail acc1
            bf16x8 ah = ld8(Ah + 512), al = ld8(Al + 512);
            acc1 = mfma16(ah, xh1, acc1);
            acc1 = mfma16(ah, xl1, acc1);
            acc1 = mfma16(al, xh1, acc1);
        }
        {   // epilogue B: cell (i0, col1) -> Ho bytes [512,1024)
            float g = tanh_fast(acc1[0]), ii = sigm(acc1[1]);
            float f = sigm(acc1[2]),      o  = sigm(acc1[3]);
            c1 = g * ii + c1 * f;
            float h = tanh_fast(c1) * o;
            Ho[(16 + lr) * 16 + r16] = f2bf(h);
            if (t == Tdim - 1) Hf32[(size_t)col1 * Hdim + i0] = h;
        }
        __syncthreads();     // S5: Ho-B done; ALL waves' storeA drained
        // ---- 7. post flagA(t+1): h-A complete ----
        if (tid == 0)
            __hip_atomic_store(myflagA, (unsigned)(t + 1),
                               __ATOMIC_RELAXED, __HIP_MEMORY_SCOPE_AGENT);

        // ---- 8. storeB (bytes 512-1023) ----
        if (tid >= 128)
            stH32((unsigned*)(Whc + myblk) + tid, *(const unsigned*)&Ho[tid * 2]);

        // ---- 9. SHADOW: poll gen t+1 (all waves; A- and B-lanes parallel) ----
        pollBoth(pollpA, pollpB, (unsigned)(t + 1), lane);

        // ---- 10. SHADOW: prefetch stageA(t+1) from Whc (= next Rh) ----
        {
            const u64* s0 = (const u64*)(Whc + offA0);
            const u64* s1 = (const u64*)(Whc + offA1);
#pragma unroll
            for (int v = 0; v < 4; ++v) a0[v] = ldA(s0 + v);
#pragma unroll
            for (int v = 0; v < 4; ++v) a1[v] = ldA(s1 + v);
        }

        // ---- 11. S6: raw barrier; keep the 8 prefetch loads in flight.
        // vmcnt(8) drains anything older (storeB) but not the prefetch.
        asm volatile("s_waitcnt vmcnt(8)\n\ts_barrier" ::: "memory");
        // ---- 12. post flagB(t+1): storeB provably drained for all waves ----
        if (tid == 0)
            __hip_atomic_store(myflagB, (unsigned)(t + 1),
                               __ATOMIC_RELAXED, __HIP_MEMORY_SCOPE_AGENT);
    }
}

// ---------- output: logits + softmax, one block per batch element ----------
__global__ __launch_bounds__(64) void k_out(
    const float* __restrict__ Hf32, const float* __restrict__ w_out,
    const float* __restrict__ b_out, float* __restrict__ out) {
    int b = blockIdx.x;
    int lane = threadIdx.x;
    const f32x4* h4 = (const f32x4*)(Hf32 + (size_t)b * 512);
    f32x4 h0 = h4[lane * 2], h1 = h4[lane * 2 + 1];
    float acc[10];
#pragma unroll
    for (int c = 0; c < 10; ++c) {
        const f32x4* w4 = (const f32x4*)(w_out + c * 512);
        f32x4 w0 = w4[lane * 2], w1 = w4[lane * 2 + 1];
        acc[c] = h0[0]*w0[0] + h0[1]*w0[1] + h0[2]*w0[2] + h0[3]*w0[3]
               + h1[0]*w1[0] + h1[1]*w1[1] + h1[2]*w1[2] + h1[3]*w1[3];
    }
#pragma unroll
    for (int s = 32; s >= 1; s >>= 1)
#pragma unroll
        for (int c = 0; c < 10; ++c) acc[c] += __shfl_xor(acc[c], s, 64);
    if (lane == 0) {
        float logit[10];
#pragma unroll
        for (int c = 0; c < 10; ++c) logit[c] = acc[c] + b_out[c];
        float m = logit[0];
#pragma unroll
        for (int c = 1; c < 10; ++c) m = fmaxf(m, logit[c]);
        float e[10], sum = 0.f;
#pragma unroll
        for (int c = 0; c < 10; ++c) { e[c] = __expf(logit[c] - m); sum += e[c]; }
        float inv = 1.f / sum;
#pragma unroll
        for (int c = 0; c < 10; ++c) out[b * 10 + c] = e[c] * inv;
    }
}

extern "C" void kernel_launch(void* const* d_in, const int* in_sizes, int n_in,
                              void* d_out, int out_size, void* d_ws, size_t ws_size,
                              hipStream_t stream) {
    const float* x    = (const float*)d_in[0];
    const float* w_gx = (const float*)d_in[1];
    const float* w_gh = (const float*)d_in[2];
    const float* b_g  = (const float*)d_in[3];
    const float* w_ix = (const float*)d_in[4];
    const float* w_ih = (const float*)d_in[5];
    const float* b_i  = (const float*)d_in[6];
    const float* w_fx = (const float*)d_in[7];
    const float* w_fh = (const float*)d_in[8];
    const float* b_f  = (const float*)d_in[9];
    const float* w_ox = (const float*)d_in[10];
    const float* w_oh = (const float*)d_in[11];
    const float* b_o  = (const float*)d_in[12];
    const float* w_out = (const float*)d_in[13];
    const float* b_out = (const float*)d_in[14];
    float* out = (float*)d_out;

    char* ws = (char*)d_ws;
    size_t off = 0;
    auto alloc = [&](size_t bytes) { void* p = ws + off; off += (bytes + 255) & ~255ull; return p; };
    // flags (A+B, 32KB) | H0c contiguous -> one zeroing kernel
    unsigned*       flags = (unsigned*)alloc(32768);      // 2 x 256 WG-flags, 64B apart
    unsigned short* H0c   = (unsigned short*)alloc((size_t)Bdim * 512 * 2);
    unsigned short* H1c   = (unsigned short*)alloc((size_t)Bdim * 512 * 2);
    float*          Hf32  = (float*)alloc((size_t)Bdim * 512 * 4);
    unsigned short* Whi   = (unsigned short*)alloc(2048ull * Kpad * 2);
    unsigned short* Wlo   = (unsigned short*)alloc(2048ull * Kpad * 2);
    unsigned short* Xhi   = (unsigned short*)alloc((size_t)Tdim * Bdim * 32 * 2);
    unsigned short* Xlo   = (unsigned short*)alloc((size_t)Tdim * Bdim * 32 * 2);
    (void)ws_size; (void)in_sizes; (void)n_in; (void)out_size;

    k_prep_w<<<(2048 * Kpad + 255) / 256, 256, 0, stream>>>(
        w_gh, w_ih, w_fh, w_oh, w_gx, w_ix, w_fx, w_ox, Whi, Wlo);
    k_prep_x<<<(Tdim * Bdim * 32 + 255) / 256, 256, 0, stream>>>(x, Xhi, Xlo);
    // zero flags(32KB)+H0c(256KB): 294,912 B = 73,728 floats = 288 blocks
    k_zero<<<288, 256, 0, stream>>>((float*)flags);

    hipFuncSetAttribute((const void*)k_persist,
                        hipFuncAttributeMaxDynamicSharedMemorySize, LDS_BYTES);
    k_persist<<<dim3(256), dim3(256), LDS_BYTES, stream>>>(
        Whi, Wlo, Xhi, Xlo, H0c, H1c,
        Hf32, b_g, b_i, b_f, b_o, flags);

    k_out<<<256, 64, 0, stream>>>(Hf32, w_out, b_out, out);
}

// Round 20
// 1273.571 us; speedup vs baseline: 1884.1518x; 1884.1518x over previous
//
#include <hip/hip_runtime.h>

// LSTM H=512, B=256, T=256, D_IN=10, C=10. fp32 in/out.
// R20 = R19 with the LIVENESS BUG fixed. R19's shadow polled flagB(t+1),
// which is posted AFTER the poll in program order -> circular wait; every
// step burned the 2^16 poll guard (9.4ms/step). Fix:
//  (a) shadow polls flagA(t+1) ONLY (posted at point 7 of the same step by
//      all WGs - acyclic). stageA prefetch reads only bytes [0,512) =
//      storeA data, so flagA is the complete gate for it.
//  (b) flagB(t) polled at loop top (all waves, parallel), posted end of
//      step t-1 -> first-try hit; gates stageB via the existing S2 barrier.
// vmcnt(8)-across-S6 unchanged: poll-result-wait acks storeB; the 8 stageA
// prefetch loads stay in flight across the barrier. 5 barriers/step.

#define Hdim 512
#define Bdim 256
#define Tdim 256
#define Kpad 544          // 512 (h) + 32 (x: 10 real + 22 zero)
#define LROW 552          // weight LDS row stride (shorts)
#define PROW 520          // panel LDS col stride (shorts)
#define LDS_BYTES ((64 * LROW * 2 + 16 * PROW + 512) * 2)   // 158,976 B -> 1 WG/CU

typedef __bf16 bf16x8 __attribute__((ext_vector_type(8)));
typedef float f32x4 __attribute__((ext_vector_type(4)));
typedef unsigned long long u64;

__device__ __forceinline__ unsigned short f2bf(float f) {
    union { float f; unsigned u; } x; x.f = f;
    unsigned r = x.u + 0x7FFFu + ((x.u >> 16) & 1u);
    return (unsigned short)(r >> 16);
}
__device__ __forceinline__ float bf2f(unsigned short h) {
    union { unsigned u; float f; } x; x.u = ((unsigned)h) << 16;
    return x.f;
}
__device__ __forceinline__ bf16x8 ld8(const unsigned short* p) {
    return *reinterpret_cast<const bf16x8*>(p);
}
__device__ __forceinline__ u64 ldA(const u64* p) {   // coherent 8B load (L3)
    return __hip_atomic_load(p, __ATOMIC_RELAXED, __HIP_MEMORY_SCOPE_AGENT);
}
// write-through 4B store (agent scope -> lands at coherence point)
__device__ __forceinline__ void stH32(unsigned* p, unsigned v) {
    __hip_atomic_store(p, v, __ATOMIC_RELAXED, __HIP_MEMORY_SCOPE_AGENT);
}
__device__ __forceinline__ f32x4 mfma16(bf16x8 a, bf16x8 b, f32x4 c) {
    return __builtin_amdgcn_mfma_f32_16x16x32_bf16(a, b, c, 0, 0, 0);
}
__device__ __forceinline__ bf16x8 pack2(u64 a, u64 b) {
    union { u64 q[2]; bf16x8 v; } u; u.q[0] = a; u.q[1] = b; return u.v;
}
__device__ __forceinline__ float sigm(float x) { return 1.f / (1.f + __expf(-x)); }
__device__ __forceinline__ float tanh_fast(float x) {
    return 2.f / (1.f + __expf(-2.f * x)) - 1.f;
}
// lane-parallel poll of 32 flag lines (lanes 0-31), bounded, first check hot
__device__ __forceinline__ void poll32(const unsigned* pollp, unsigned tgt, int lane) {
    bool ok = lane >= 32;
    if (!ok) {
        unsigned v = __hip_atomic_load(pollp, __ATOMIC_RELAXED, __HIP_MEMORY_SCOPE_AGENT);
        ok = (v >= tgt);
    }
    int guard = 1 << 16;   // bounded: pathological case -> no hang
    while (!ok && --guard) {
        __builtin_amdgcn_s_sleep(1);
        unsigned v = __hip_atomic_load(pollp, __ATOMIC_RELAXED, __HIP_MEMORY_SCOPE_AGENT);
        ok = (v >= tgt);
    }
}

// ---------- prep: stacked gate weights -> bf16 hi/lo, row = 4*i + gate ----------
__global__ void k_prep_w(const float* __restrict__ w_gh, const float* __restrict__ w_ih,
                         const float* __restrict__ w_fh, const float* __restrict__ w_oh,
                         const float* __restrict__ w_gx, const float* __restrict__ w_ix,
                         const float* __restrict__ w_fx, const float* __restrict__ w_ox,
                         unsigned short* __restrict__ Whi, unsigned short* __restrict__ Wlo) {
    int idx = blockIdx.x * 256 + threadIdx.x;
    if (idx >= 2048 * Kpad) return;
    int rw = idx / Kpad;
    int k  = idx % Kpad;
    int gate = rw & 3;
    int i = rw >> 2;
    float v = 0.f;
    if (k < 512) {
        const float* wh = (gate == 0) ? w_gh : (gate == 1) ? w_ih : (gate == 2) ? w_fh : w_oh;
        v = wh[i * 512 + k];
    } else if (k < 522) {
        const float* wx = (gate == 0) ? w_gx : (gate == 1) ? w_ix : (gate == 2) ? w_fx : w_ox;
        v = wx[i * 10 + (k - 512)];
    }
    unsigned short hi = f2bf(v);
    unsigned short lo = f2bf(v - bf2f(hi));
    Whi[idx] = hi;
    Wlo[idx] = lo;
}

// ---------- prep: x -> Xhi/Xlo [t][b][32] ----------
__global__ void k_prep_x(const float* __restrict__ x,
                         unsigned short* __restrict__ Xhi, unsigned short* __restrict__ Xlo) {
    int idx = blockIdx.x * 256 + threadIdx.x;
    if (idx >= Tdim * Bdim * 32) return;
    int j = idx & 31;
    int b = (idx >> 5) & 255;
    int t = idx >> 13;
    float v = 0.f;
    if (j < 10) v = x[(b * Tdim + t) * 10 + j];
    unsigned short hi = f2bf(v);
    unsigned short lo = f2bf(v - bf2f(hi));
    Xhi[idx] = hi;
    Xlo[idx] = lo;
}

__global__ void k_zero(float* __restrict__ p) {
    p[blockIdx.x * 256 + threadIdx.x] = 0.f;
}

// ---------- persistent LSTM ----------
// 256 WGs x 256 thr. WG: 64 stacked rows x 32 cols. Wave w: rows w*16..+15.
// h layout: Hc[((ct*32+rg)*32 + col_local)*16 + r16] -> 1KB/WG contiguous.
__global__ __launch_bounds__(256, 1) void k_persist(
    const unsigned short* __restrict__ Whi, const unsigned short* __restrict__ Wlo,
    const unsigned short* __restrict__ Xhi, const unsigned short* __restrict__ Xlo,
    unsigned short* H0c, unsigned short* H1c,
    float* __restrict__ Hf32,
    const float* __restrict__ bg, const float* __restrict__ bi,
    const float* __restrict__ bf_, const float* __restrict__ bo,
    unsigned* flags) {
    extern __shared__ unsigned short lds[];
    unsigned short* Lhi = lds;                       // [64][LROW]
    unsigned short* Llo = lds + 64 * LROW;           // [64][LROW]
    unsigned short* Pp  = lds + 64 * LROW * 2;       // [16][PROW] panel
    unsigned short* Ho  = Pp + 16 * PROW;            // [32][16] h-out bounce

    const int bid = blockIdx.x;
    const int rg  = bid >> 3;                  // row-group id (0..31)
    const int m0  = rg * 64;                   // stacked-row tile base
    const int ct  = bid & 7;                   // column-group id
    const int bn0 = ct * 32;
    const int tid = threadIdx.x;
    const int lane = tid & 63;
    const int w  = tid >> 6;                   // wave id: rows w*16..w*16+15
    const int lr = lane & 15, q = lane >> 4;

    // flags: flagsA = flags[0..4095], flagsB = flags[4096..8191] (uints)
    unsigned* flagsA = flags;
    unsigned* flagsB = flags + 4096;
    unsigned* myflagA = flagsA + (((ct << 5) + rg) << 4);
    unsigned* myflagB = flagsB + (((ct << 5) + rg) << 4);
    const unsigned* pollpA = flagsA + (((ct << 5) + (lane & 31)) << 4);
    const unsigned* pollpB = flagsB + (((ct << 5) + (lane & 31)) << 4);

    // panel staging role: thread (cl = tid>>4, e = tid&15)
    const int cl = tid >> 4;
    const int e  = tid & 15;

    // one-time weight staging global -> LDS
    for (int it = tid; it < 64 * 68; it += 256) {
        int r = it / 68, c8 = (it % 68) * 8;
        *(bf16x8*)&Lhi[r * LROW + c8] = ld8(Whi + (size_t)(m0 + r) * Kpad + c8);
        *(bf16x8*)&Llo[r * LROW + c8] = ld8(Wlo + (size_t)(m0 + r) * Kpad + c8);
    }
    __syncthreads();

    const int kq = q * 8;
    const int col0 = bn0 + lr;                 // acc0 cell column (phase A)
    const int col1 = col0 + 16;                // acc1 cell column (phase B)
    const int i0 = rg * 16 + w * 4 + q;        // h-row of both cells
    const int r16 = w * 4 + q;                 // row%16

    float c0 = 0.f, c1 = 0.f;
    const f32x4 binit = { bg[i0], bi[i0], bf_[i0], bo[i0] };

    const unsigned short* Ah = &Lhi[(w * 16 + lr) * LROW + kq];
    const unsigned short* Al = &Llo[(w * 16 + lr) * LROW + kq];
    const unsigned short* Bl = &Pp[lr * PROW + kq];
    unsigned short* Pd0 = &Pp[cl * PROW + e * 16];        // rows of rg=e
    unsigned short* Pd1 = &Pp[cl * PROW + e * 16 + 256];  // rows of rg=e+16

    // global h block base (compact layout)
    const size_t myblk = ((size_t)ct * 32 + rg) * 512;    // this WG's 1KB block

    // source offsets for staging (within an Hc buffer)
    const size_t offA0 = (((size_t)ct * 32 + e) * 32 + cl) * 16;
    const size_t offA1 = (((size_t)ct * 32 + e + 16) * 32 + cl) * 16;
    const size_t offB0 = (((size_t)ct * 32 + e) * 32 + 16 + cl) * 16;
    const size_t offB1 = (((size_t)ct * 32 + e + 16) * 32 + 16 + cl) * 16;

    // ---- prologue: stageA(0) prefetch (H0c zeroed; gen-0 gates trivially true)
    u64 a0[4], a1[4];
    {
        const u64* s0 = (const u64*)(H0c + offA0);
        const u64* s1 = (const u64*)(H0c + offA1);
#pragma unroll
        for (int v = 0; v < 4; ++v) a0[v] = ldA(s0 + v);
#pragma unroll
        for (int v = 0; v < 4; ++v) a1[v] = ldA(s1 + v);
    }

    for (int t = 0; t < Tdim; ++t) {
        const unsigned short* Rh = (t & 1) ? H1c : H0c;   // holds h(t-1)
        unsigned short* Whc = (t & 1) ? H0c : H1c;        // receives h(t)

        // ---- 1. write panel A from prefetched regs ----
        *(bf16x8*)(Pd0)     = pack2(a0[0], a0[1]);
        *(bf16x8*)(Pd0 + 8) = pack2(a0[2], a0[3]);
        *(bf16x8*)(Pd1)     = pack2(a1[0], a1[1]);
        *(bf16x8*)(Pd1 + 8) = pack2(a1[2], a1[3]);

        // ---- 1b. gate B: flagB(t) (posted end of step t-1 -> first-try hit)
        poll32(pollpB, (unsigned)t, lane);
        __syncthreads();                       // S2: panel A ready + B gated

        // ---- 2. stageB(t) loads + x fragments ----
        u64 b0[4], b1[4];
        {
            const u64* s0 = (const u64*)(Rh + offB0);
            const u64* s1 = (const u64*)(Rh + offB1);
#pragma unroll
            for (int v = 0; v < 4; ++v) b0[v] = ldA(s0 + v);
#pragma unroll
            for (int v = 0; v < 4; ++v) b1[v] = ldA(s1 + v);
        }
        const unsigned short* xb  = Xhi + ((size_t)t * Bdim) * 32;
        const unsigned short* xbl = Xlo + ((size_t)t * Bdim) * 32;
        bf16x8 xh0 = ld8(xb + col0 * 32 + kq), xl0 = ld8(xbl + col0 * 32 + kq);
        bf16x8 xh1 = ld8(xb + col1 * 32 + kq), xl1 = ld8(xbl + col1 * 32 + kq);

        // ---- 3. MFMA phase A (cols 0-15) -> acc0 ----
        f32x4 acc0 = binit, acc1 = binit;
#pragma unroll
        for (int kb = 0; kb < 16; ++kb) {
            const int k = kb * 32;
            bf16x8 ah = ld8(Ah + k), al = ld8(Al + k);
            bf16x8 bh = ld8(Bl + k);
            acc0 = mfma16(ah, bh, acc0);
            acc0 = mfma16(al, bh, acc0);
        }
        {   // x tail acc0
            bf16x8 ah = ld8(Ah + 512), al = ld8(Al + 512);
            acc0 = mfma16(ah, xh0, acc0);
            acc0 = mfma16(ah, xl0, acc0);
            acc0 = mfma16(al, xh0, acc0);
        }
        {   // epilogue A: cell (i0, col0) -> Ho bytes [0,512)
            float g = tanh_fast(acc0[0]), ii = sigm(acc0[1]);
            float f = sigm(acc0[2]),      o  = sigm(acc0[3]);
            c0 = g * ii + c0 * f;
            float h = tanh_fast(c0) * o;
            Ho[lr * 16 + r16] = f2bf(h);
            if (t == Tdim - 1) Hf32[(size_t)col0 * Hdim + i0] = h;
        }
        __syncthreads();                       // S3: panel A consumed + Ho-A done

        // ---- 4. write panel B (stageB data) ----
        *(bf16x8*)(Pd0)     = pack2(b0[0], b0[1]);
        *(bf16x8*)(Pd0 + 8) = pack2(b0[2], b0[3]);
        *(bf16x8*)(Pd1)     = pack2(b1[0], b1[1]);
        *(bf16x8*)(Pd1 + 8) = pack2(b1[2], b1[3]);
        __syncthreads();                       // S4: panel B ready

        // ---- 5. storeA (coalesced, bytes 0-511) overlapped with MFMA-B ----
        if (tid < 128)
            stH32((unsigned*)(Whc + myblk) + tid, *(const unsigned*)&Ho[tid * 2]);

        // ---- 6. MFMA phase B (cols 16-31) -> acc1 ----
#pragma unroll
        for (int kb = 0; kb < 16; ++kb) {
            const int k = kb * 32;
            bf16x8 ah = ld8(Ah + k), al = ld8(Al + k);
            bf16x8 bh = ld8(Bl + k);
            acc1 = mfma16(ah, bh, acc1);
            acc1 = mfma16(al, bh, acc1);
        }
        {   // x tail acc1
            bf16x8 ah = ld8(Ah + 512), al = ld8(Al + 512);
            acc1 = mfma16(ah, xh1, acc1);
            acc1 = mfma16(ah, xl1, acc1);
            acc1 = mfma16(al, xh1, acc1);
        }
        {   // epilogue B: cell (i0, col1) -> Ho bytes [512,1024)
            float g = tanh_fast(acc1[0]), ii = sigm(acc1[1]);
            float f = sigm(acc1[2]),      o  = sigm(acc1[3]);
            c1 = g * ii + c1 * f;
            float h = tanh_fast(c1) * o;
            Ho[(16 + lr) * 16 + r16] = f2bf(h);
            if (t == Tdim - 1) Hf32[(size_t)col1 * Hdim + i0] = h;
        }
        __syncthreads();     // S5: Ho-B done; ALL waves' storeA drained
        // ---- 7. post flagA(t+1): h-A complete ----
        if (tid == 0)
            __hip_atomic_store(myflagA, (unsigned)(t + 1),
                               __ATOMIC_RELAXED, __HIP_MEMORY_SCOPE_AGENT);

        // ---- 8. storeB (bytes 512-1023) ----
        if (tid >= 128)
            stH32((unsigned*)(Whc + myblk) + tid, *(const unsigned*)&Ho[tid * 2]);

        // ---- 9. SHADOW: poll flagA(t+1) only (posted at 7 by all WGs) ----
        poll32(pollpA, (unsigned)(t + 1), lane);

        // ---- 10. SHADOW: prefetch stageA(t+1) (gated by flagA alone:
        //          reads bytes [0,512) = storeA data) ----
        {
            const u64* s0 = (const u64*)(Whc + offA0);
            const u64* s1 = (const u64*)(Whc + offA1);
#pragma unroll
            for (int v = 0; v < 4; ++v) a0[v] = ldA(s0 + v);
#pragma unroll
            for (int v = 0; v < 4; ++v) a1[v] = ldA(s1 + v);
        }

        // ---- 11. S6: raw barrier; keep 8 prefetch loads in flight.
        // vmcnt(8) drains older ops (storeB) but not the prefetch.
        asm volatile("s_waitcnt vmcnt(8)\n\ts_barrier" ::: "memory");
        // ---- 12. post flagB(t+1): storeB provably drained for all waves ----
        if (tid == 0)
            __hip_atomic_store(myflagB, (unsigned)(t + 1),
                               __ATOMIC_RELAXED, __HIP_MEMORY_SCOPE_AGENT);
    }
}

// ---------- output: logits + softmax, one block per batch element ----------
__global__ __launch_bounds__(64) void k_out(
    const float* __restrict__ Hf32, const float* __restrict__ w_out,
    const float* __restrict__ b_out, float* __restrict__ out) {
    int b = blockIdx.x;
    int lane = threadIdx.x;
    const f32x4* h4 = (const f32x4*)(Hf32 + (size_t)b * 512);
    f32x4 h0 = h4[lane * 2], h1 = h4[lane * 2 + 1];
    float acc[10];
#pragma unroll
    for (int c = 0; c < 10; ++c) {
        const f32x4* w4 = (const f32x4*)(w_out + c * 512);
        f32x4 w0 = w4[lane * 2], w1 = w4[lane * 2 + 1];
        acc[c] = h0[0]*w0[0] + h0[1]*w0[1] + h0[2]*w0[2] + h0[3]*w0[3]
               + h1[0]*w1[0] + h1[1]*w1[1] + h1[2]*w1[2] + h1[3]*w1[3];
    }
#pragma unroll
    for (int s = 32; s >= 1; s >>= 1)
#pragma unroll
        for (int c = 0; c < 10; ++c) acc[c] += __shfl_xor(acc[c], s, 64);
    if (lane == 0) {
        float logit[10];
#pragma unroll
        for (int c = 0; c < 10; ++c) logit[c] = acc[c] + b_out[c];
        float m = logit[0];
#pragma unroll
        for (int c = 1; c < 10; ++c) m = fmaxf(m, logit[c]);
        float e[10], sum = 0.f;
#pragma unroll
        for (int c = 0; c < 10; ++c) { e[c] = __expf(logit[c] - m); sum += e[c]; }
        float inv = 1.f / sum;
#pragma unroll
        for (int c = 0; c < 10; ++c) out[b * 10 + c] = e[c] * inv;
    }
}

extern "C" void kernel_launch(void* const* d_in, const int* in_sizes, int n_in,
                              void* d_out, int out_size, void* d_ws, size_t ws_size,
                              hipStream_t stream) {
    const float* x    = (const float*)d_in[0];
    const float* w_gx = (const float*)d_in[1];
    const float* w_gh = (const float*)d_in[2];
    const float* b_g  = (const float*)d_in[3];
    const float* w_ix = (const float*)d_in[4];
    const float* w_ih = (const float*)d_in[5];
    const float* b_i  = (const float*)d_in[6];
    const float* w_fx = (const float*)d_in[7];
    const float* w_fh = (const float*)d_in[8];
    const float* b_f  = (const float*)d_in[9];
    const float* w_ox = (const float*)d_in[10];
    const float* w_oh = (const float*)d_in[11];
    const float* b_o  = (const float*)d_in[12];
    const float* w_out = (const float*)d_in[13];
    const float* b_out = (const float*)d_in[14];
    float* out = (float*)d_out;

    char* ws = (char*)d_ws;
    size_t off = 0;
    auto alloc = [&](size_t bytes) { void* p = ws + off; off += (bytes + 255) & ~255ull; return p; };
    // flags (A+B, 32KB) | H0c contiguous -> one zeroing kernel
    unsigned*       flags = (unsigned*)alloc(32768);      // 2 x 256 WG-flags, 64B apart
    unsigned short* H0c   = (unsigned short*)alloc((size_t)Bdim * 512 * 2);
    unsigned short* H1c   = (unsigned short*)alloc((size_t)Bdim * 512 * 2);
    float*          Hf32  = (float*)alloc((size_t)Bdim * 512 * 4);
    unsigned short* Whi   = (unsigned short*)alloc(2048ull * Kpad * 2);
    unsigned short* Wlo   = (unsigned short*)alloc(2048ull * Kpad * 2);
    unsigned short* Xhi   = (unsigned short*)alloc((size_t)Tdim * Bdim * 32 * 2);
    unsigned short* Xlo   = (unsigned short*)alloc((size_t)Tdim * Bdim * 32 * 2);
    (void)ws_size; (void)in_sizes; (void)n_in; (void)out_size;

    k_prep_w<<<(2048 * Kpad + 255) / 256, 256, 0, stream>>>(
        w_gh, w_ih, w_fh, w_oh, w_gx, w_ix, w_fx, w_ox, Whi, Wlo);
    k_prep_x<<<(Tdim * Bdim * 32 + 255) / 256, 256, 0, stream>>>(x, Xhi, Xlo);
    // zero flags(32KB)+H0c(256KB): 294,912 B = 73,728 floats = 288 blocks
    k_zero<<<288, 256, 0, stream>>>((float*)flags);

    hipFuncSetAttribute((const void*)k_persist,
                        hipFuncAttributeMaxDynamicSharedMemorySize, LDS_BYTES);
    k_persist<<<dim3(256), dim3(256), LDS_BYTES, stream>>>(
        Whi, Wlo, Xhi, Xlo, H0c, H1c,
        Hf32, b_g, b_i, b_f, b_o, flags);

    k_out<<<256, 64, 0, stream>>>(Hf32, w_out, b_out, out);
}

// Round 21
// 1132.818 us; speedup vs baseline: 2118.2585x; 1.1243x over previous
//
#include <hip/hip_runtime.h>

// LSTM H=512, B=256, T=256, D_IN=10, C=10. fp32 in/out.
// R21 = R18 + shadow stageA-prefetch with CORRECT placement (R20 post-mortem:
// putting the shadow pollA before flagB posting delayed flagB -> cascading
// +0.55us/step). Order now: ... S5 -> flagA -> storeB -> S6 -> flagB ->
// {shadow: pollA(t+1), prefetch stageA(t+1)} -> loop. flagB is never gated by
// a poll; shadow pollA is acyclic (flagA(t+1) depends only on flagB(t)).
// Prefetch is issued after S6 and consumed before next S2 -> crosses NO
// barrier; all barriers are plain __syncthreads (no raw-asm vmcnt tricks).
// 5 barriers/step. pollB(t) at loop top, all-waves-parallel.

#define Hdim 512
#define Bdim 256
#define Tdim 256
#define Kpad 544          // 512 (h) + 32 (x: 10 real + 22 zero)
#define LROW 552          // weight LDS row stride (shorts)
#define PROW 520          // panel LDS col stride (shorts)
#define LDS_BYTES ((64 * LROW * 2 + 16 * PROW + 512) * 2)   // 158,976 B -> 1 WG/CU

typedef __bf16 bf16x8 __attribute__((ext_vector_type(8)));
typedef float f32x4 __attribute__((ext_vector_type(4)));
typedef unsigned long long u64;

__device__ __forceinline__ unsigned short f2bf(float f) {
    union { float f; unsigned u; } x; x.f = f;
    unsigned r = x.u + 0x7FFFu + ((x.u >> 16) & 1u);
    return (unsigned short)(r >> 16);
}
__device__ __forceinline__ float bf2f(unsigned short h) {
    union { unsigned u; float f; } x; x.u = ((unsigned)h) << 16;
    return x.f;
}
__device__ __forceinline__ bf16x8 ld8(const unsigned short* p) {
    return *reinterpret_cast<const bf16x8*>(p);
}
__device__ __forceinline__ u64 ldA(const u64* p) {   // coherent 8B load (L3)
    return __hip_atomic_load(p, __ATOMIC_RELAXED, __HIP_MEMORY_SCOPE_AGENT);
}
// write-through 4B store (agent scope -> lands at coherence point)
__device__ __forceinline__ void stH32(unsigned* p, unsigned v) {
    __hip_atomic_store(p, v, __ATOMIC_RELAXED, __HIP_MEMORY_SCOPE_AGENT);
}
__device__ __forceinline__ f32x4 mfma16(bf16x8 a, bf16x8 b, f32x4 c) {
    return __builtin_amdgcn_mfma_f32_16x16x32_bf16(a, b, c, 0, 0, 0);
}
__device__ __forceinline__ bf16x8 pack2(u64 a, u64 b) {
    union { u64 q[2]; bf16x8 v; } u; u.q[0] = a; u.q[1] = b; return u.v;
}
__device__ __forceinline__ float sigm(float x) { return 1.f / (1.f + __expf(-x)); }
__device__ __forceinline__ float tanh_fast(float x) {
    return 2.f / (1.f + __expf(-2.f * x)) - 1.f;
}
// lane-parallel poll of the 32 flag lines (lanes 0-31), bounded, first check hot
__device__ __forceinline__ void poll32(const unsigned* pollp, unsigned tgt, int lane) {
    bool ok = lane >= 32;
    if (!ok) {
        unsigned v = __hip_atomic_load(pollp, __ATOMIC_RELAXED, __HIP_MEMORY_SCOPE_AGENT);
        ok = (v >= tgt);
    }
    int guard = 1 << 16;   // bounded: pathological case -> no hang
    while (!ok && --guard) {
        __builtin_amdgcn_s_sleep(1);
        unsigned v = __hip_atomic_load(pollp, __ATOMIC_RELAXED, __HIP_MEMORY_SCOPE_AGENT);
        ok = (v >= tgt);
    }
}

// ---------- prep: stacked gate weights -> bf16 hi/lo, row = 4*i + gate ----------
__global__ void k_prep_w(const float* __restrict__ w_gh, const float* __restrict__ w_ih,
                         const float* __restrict__ w_fh, const float* __restrict__ w_oh,
                         const float* __restrict__ w_gx, const float* __restrict__ w_ix,
                         const float* __restrict__ w_fx, const float* __restrict__ w_ox,
                         unsigned short* __restrict__ Whi, unsigned short* __restrict__ Wlo) {
    int idx = blockIdx.x * 256 + threadIdx.x;
    if (idx >= 2048 * Kpad) return;
    int rw = idx / Kpad;
    int k  = idx % Kpad;
    int gate = rw & 3;
    int i = rw >> 2;
    float v = 0.f;
    if (k < 512) {
        const float* wh = (gate == 0) ? w_gh : (gate == 1) ? w_ih : (gate == 2) ? w_fh : w_oh;
        v = wh[i * 512 + k];
    } else if (k < 522) {
        const float* wx = (gate == 0) ? w_gx : (gate == 1) ? w_ix : (gate == 2) ? w_fx : w_ox;
        v = wx[i * 10 + (k - 512)];
    }
    unsigned short hi = f2bf(v);
    unsigned short lo = f2bf(v - bf2f(hi));
    Whi[idx] = hi;
    Wlo[idx] = lo;
}

// ---------- prep: x -> Xhi/Xlo [t][b][32] ----------
__global__ void k_prep_x(const float* __restrict__ x,
                         unsigned short* __restrict__ Xhi, unsigned short* __restrict__ Xlo) {
    int idx = blockIdx.x * 256 + threadIdx.x;
    if (idx >= Tdim * Bdim * 32) return;
    int j = idx & 31;
    int b = (idx >> 5) & 255;
    int t = idx >> 13;
    float v = 0.f;
    if (j < 10) v = x[(b * Tdim + t) * 10 + j];
    unsigned short hi = f2bf(v);
    unsigned short lo = f2bf(v - bf2f(hi));
    Xhi[idx] = hi;
    Xlo[idx] = lo;
}

__global__ void k_zero(float* __restrict__ p) {
    p[blockIdx.x * 256 + threadIdx.x] = 0.f;
}

// ---------- persistent LSTM ----------
// 256 WGs x 256 thr. WG: 64 stacked rows x 32 cols. Wave w: rows w*16..+15.
// h layout: Hc[((ct*32+rg)*32 + col_local)*16 + r16] -> 1KB/WG contiguous.
__global__ __launch_bounds__(256, 1) void k_persist(
    const unsigned short* __restrict__ Whi, const unsigned short* __restrict__ Wlo,
    const unsigned short* __restrict__ Xhi, const unsigned short* __restrict__ Xlo,
    unsigned short* H0c, unsigned short* H1c,
    float* __restrict__ Hf32,
    const float* __restrict__ bg, const float* __restrict__ bi,
    const float* __restrict__ bf_, const float* __restrict__ bo,
    unsigned* flags) {
    extern __shared__ unsigned short lds[];
    unsigned short* Lhi = lds;                       // [64][LROW]
    unsigned short* Llo = lds + 64 * LROW;           // [64][LROW]
    unsigned short* Pp  = lds + 64 * LROW * 2;       // [16][PROW] panel
    unsigned short* Ho  = Pp + 16 * PROW;            // [32][16] h-out bounce

    const int bid = blockIdx.x;
    const int rg  = bid >> 3;                  // row-group id (0..31)
    const int m0  = rg * 64;                   // stacked-row tile base
    const int ct  = bid & 7;                   // column-group id
    const int bn0 = ct * 32;
    const int tid = threadIdx.x;
    const int lane = tid & 63;
    const int w  = tid >> 6;                   // wave id: rows w*16..w*16+15
    const int lr = lane & 15, q = lane >> 4;

    // flags: flagsA = flags[0..4095], flagsB = flags[4096..8191] (uints)
    unsigned* flagsA = flags;
    unsigned* flagsB = flags + 4096;
    unsigned* myflagA = flagsA + (((ct << 5) + rg) << 4);
    unsigned* myflagB = flagsB + (((ct << 5) + rg) << 4);
    const unsigned* pollpA = flagsA + (((ct << 5) + (lane & 31)) << 4);
    const unsigned* pollpB = flagsB + (((ct << 5) + (lane & 31)) << 4);

    // panel staging role: thread (cl = tid>>4, e = tid&15)
    const int cl = tid >> 4;
    const int e  = tid & 15;

    // one-time weight staging global -> LDS
    for (int it = tid; it < 64 * 68; it += 256) {
        int r = it / 68, c8 = (it % 68) * 8;
        *(bf16x8*)&Lhi[r * LROW + c8] = ld8(Whi + (size_t)(m0 + r) * Kpad + c8);
        *(bf16x8*)&Llo[r * LROW + c8] = ld8(Wlo + (size_t)(m0 + r) * Kpad + c8);
    }
    __syncthreads();

    const int kq = q * 8;
    const int col0 = bn0 + lr;                 // acc0 cell column (phase A)
    const int col1 = col0 + 16;                // acc1 cell column (phase B)
    const int i0 = rg * 16 + w * 4 + q;        // h-row of both cells
    const int r16 = w * 4 + q;                 // row%16

    float c0 = 0.f, c1 = 0.f;
    const f32x4 binit = { bg[i0], bi[i0], bf_[i0], bo[i0] };

    const unsigned short* Ah = &Lhi[(w * 16 + lr) * LROW + kq];
    const unsigned short* Al = &Llo[(w * 16 + lr) * LROW + kq];
    const unsigned short* Bl = &Pp[lr * PROW + kq];
    unsigned short* Pd0 = &Pp[cl * PROW + e * 16];        // rows of rg=e
    unsigned short* Pd1 = &Pp[cl * PROW + e * 16 + 256];  // rows of rg=e+16

    // global h block base (compact layout)
    const size_t myblk = ((size_t)ct * 32 + rg) * 512;    // this WG's 1KB block

    // source offsets for staging (within an Hc buffer)
    const size_t offA0 = (((size_t)ct * 32 + e) * 32 + cl) * 16;
    const size_t offA1 = (((size_t)ct * 32 + e + 16) * 32 + cl) * 16;
    const size_t offB0 = (((size_t)ct * 32 + e) * 32 + 16 + cl) * 16;
    const size_t offB1 = (((size_t)ct * 32 + e + 16) * 32 + 16 + cl) * 16;

    // ---- prologue: stageA(0) prefetch (H0c zeroed; gen-0 gates trivially true)
    u64 a0[4], a1[4];
    {
        const u64* s0 = (const u64*)(H0c + offA0);
        const u64* s1 = (const u64*)(H0c + offA1);
#pragma unroll
        for (int v = 0; v < 4; ++v) a0[v] = ldA(s0 + v);
#pragma unroll
        for (int v = 0; v < 4; ++v) a1[v] = ldA(s1 + v);
    }

    for (int t = 0; t < Tdim; ++t) {
        const unsigned short* Rh = (t & 1) ? H1c : H0c;   // holds h(t-1)
        unsigned short* Whc = (t & 1) ? H0c : H1c;        // receives h(t)

        // ---- 1. write panel A from prefetched regs ----
        *(bf16x8*)(Pd0)     = pack2(a0[0], a0[1]);
        *(bf16x8*)(Pd0 + 8) = pack2(a0[2], a0[3]);
        *(bf16x8*)(Pd1)     = pack2(a1[0], a1[1]);
        *(bf16x8*)(Pd1 + 8) = pack2(a1[2], a1[3]);

        // ---- 1b. gate B: flagB(t) (posted end of step t-1, parallel poll) ----
        poll32(pollpB, (unsigned)t, lane);
        __syncthreads();                       // S2: panel A ready + B gated

        // ---- 2. stageB(t) loads + x fragments ----
        u64 b0[4], b1[4];
        {
            const u64* s0 = (const u64*)(Rh + offB0);
            const u64* s1 = (const u64*)(Rh + offB1);
#pragma unroll
            for (int v = 0; v < 4; ++v) b0[v] = ldA(s0 + v);
#pragma unroll
            for (int v = 0; v < 4; ++v) b1[v] = ldA(s1 + v);
        }
        const unsigned short* xb  = Xhi + ((size_t)t * Bdim) * 32;
        const unsigned short* xbl = Xlo + ((size_t)t * Bdim) * 32;
        bf16x8 xh0 = ld8(xb + col0 * 32 + kq), xl0 = ld8(xbl + col0 * 32 + kq);
        bf16x8 xh1 = ld8(xb + col1 * 32 + kq), xl1 = ld8(xbl + col1 * 32 + kq);

        // ---- 3. MFMA phase A (cols 0-15) -> acc0 ----
        f32x4 acc0 = binit, acc1 = binit;
#pragma unroll
        for (int kb = 0; kb < 16; ++kb) {
            const int k = kb * 32;
            bf16x8 ah = ld8(Ah + k), al = ld8(Al + k);
            bf16x8 bh = ld8(Bl + k);
            acc0 = mfma16(ah, bh, acc0);
            acc0 = mfma16(al, bh, acc0);
        }
        {   // x tail acc0
            bf16x8 ah = ld8(Ah + 512), al = ld8(Al + 512);
            acc0 = mfma16(ah, xh0, acc0);
            acc0 = mfma16(ah, xl0, acc0);
            acc0 = mfma16(al, xh0, acc0);
        }
        {   // epilogue A: cell (i0, col0) -> Ho bytes [0,512)
            float g = tanh_fast(acc0[0]), ii = sigm(acc0[1]);
            float f = sigm(acc0[2]),      o  = sigm(acc0[3]);
            c0 = g * ii + c0 * f;
            float h = tanh_fast(c0) * o;
            Ho[lr * 16 + r16] = f2bf(h);
            if (t == Tdim - 1) Hf32[(size_t)col0 * Hdim + i0] = h;
        }
        __syncthreads();                       // S3: panel A consumed + Ho-A done

        // ---- 4. write panel B (stageB data) ----
        *(bf16x8*)(Pd0)     = pack2(b0[0], b0[1]);
        *(bf16x8*)(Pd0 + 8) = pack2(b0[2], b0[3]);
        *(bf16x8*)(Pd1)     = pack2(b1[0], b1[1]);
        *(bf16x8*)(Pd1 + 8) = pack2(b1[2], b1[3]);
        __syncthreads();                       // S4: panel B ready

        // ---- 5. storeA (coalesced, bytes 0-511) overlapped with MFMA-B ----
        if (tid < 128)
            stH32((unsigned*)(Whc + myblk) + tid, *(const unsigned*)&Ho[tid * 2]);

        // ---- 6. MFMA phase B (cols 16-31) -> acc1 ----
#pragma unroll
        for (int kb = 0; kb < 16; ++kb) {
            const int k = kb * 32;
            bf16x8 ah = ld8(Ah + k), al = ld8(Al + k);
            bf16x8 bh = ld8(Bl + k);
            acc1 = mfma16(ah, bh, acc1);
            acc1 = mfma16(al, bh, acc1);
        }
        {   // x tail acc1
            bf16x8 ah = ld8(Ah + 512), al = ld8(Al + 512);
            acc1 = mfma16(ah, xh1, acc1);
            acc1 = mfma16(ah, xl1, acc1);
            acc1 = mfma16(al, xh1, acc1);
        }
        {   // epilogue B: cell (i0, col1) -> Ho bytes [512,1024)
            float g = tanh_fast(acc1[0]), ii = sigm(acc1[1]);
            float f = sigm(acc1[2]),      o  = sigm(acc1[3]);
            c1 = g * ii + c1 * f;
            float h = tanh_fast(c1) * o;
            Ho[(16 + lr) * 16 + r16] = f2bf(h);
            if (t == Tdim - 1) Hf32[(size_t)col1 * Hdim + i0] = h;
        }
        __syncthreads();     // S5: Ho-B done; ALL waves' storeA drained
        // ---- 7. post flagA(t+1): h-A complete (safe: S5 drained storeA) ----
        if (tid == 0)
            __hip_atomic_store(myflagA, (unsigned)(t + 1),
                               __ATOMIC_RELAXED, __HIP_MEMORY_SCOPE_AGENT);

        // ---- 8. storeB (bytes 512-1023) ----
        if (tid >= 128)
            stH32((unsigned*)(Whc + myblk) + tid, *(const unsigned*)&Ho[tid * 2]);
        __syncthreads();     // S6: all waves' storeB drained
        // ---- 9. post flagB(t+1) IMMEDIATELY (never gated by a poll) ----
        if (tid == 0)
            __hip_atomic_store(myflagB, (unsigned)(t + 1),
                               __ATOMIC_RELAXED, __HIP_MEMORY_SCOPE_AGENT);

        // ---- 10. SHADOW (after flagB): pollA(t+1) + prefetch stageA(t+1).
        // Acyclic: flagA(t+1) depends only on flagB(t). Prefetch reads bytes
        // [0,512) = storeA data, fully gated by flagA. Loads consumed at next
        // loop-top panel-A write -> cross no barrier.
        if (t < Tdim - 1) {
            poll32(pollpA, (unsigned)(t + 1), lane);
            const u64* s0 = (const u64*)(Whc + offA0);
            const u64* s1 = (const u64*)(Whc + offA1);
#pragma unroll
            for (int v = 0; v < 4; ++v) a0[v] = ldA(s0 + v);
#pragma unroll
            for (int v = 0; v < 4; ++v) a1[v] = ldA(s1 + v);
        }
    }
}

// ---------- output: logits + softmax, one block per batch element ----------
__global__ __launch_bounds__(64) void k_out(
    const float* __restrict__ Hf32, const float* __restrict__ w_out,
    const float* __restrict__ b_out, float* __restrict__ out) {
    int b = blockIdx.x;
    int lane = threadIdx.x;
    const f32x4* h4 = (const f32x4*)(Hf32 + (size_t)b * 512);
    f32x4 h0 = h4[lane * 2], h1 = h4[lane * 2 + 1];
    float acc[10];
#pragma unroll
    for (int c = 0; c < 10; ++c) {
        const f32x4* w4 = (const f32x4*)(w_out + c * 512);
        f32x4 w0 = w4[lane * 2], w1 = w4[lane * 2 + 1];
        acc[c] = h0[0]*w0[0] + h0[1]*w0[1] + h0[2]*w0[2] + h0[3]*w0[3]
               + h1[0]*w1[0] + h1[1]*w1[1] + h1[2]*w1[2] + h1[3]*w1[3];
    }
#pragma unroll
    for (int s = 32; s >= 1; s >>= 1)
#pragma unroll
        for (int c = 0; c < 10; ++c) acc[c] += __shfl_xor(acc[c], s, 64);
    if (lane == 0) {
        float logit[10];
#pragma unroll
        for (int c = 0; c < 10; ++c) logit[c] = acc[c] + b_out[c];
        float m = logit[0];
#pragma unroll
        for (int c = 1; c < 10; ++c) m = fmaxf(m, logit[c]);
        float e[10], sum = 0.f;
#pragma unroll
        for (int c = 0; c < 10; ++c) { e[c] = __expf(logit[c] - m); sum += e[c]; }
        float inv = 1.f / sum;
#pragma unroll
        for (int c = 0; c < 10; ++c) out[b * 10 + c] = e[c] * inv;
    }
}

extern "C" void kernel_launch(void* const* d_in, const int* in_sizes, int n_in,
                              void* d_out, int out_size, void* d_ws, size_t ws_size,
                              hipStream_t stream) {
    const float* x    = (const float*)d_in[0];
    const float* w_gx = (const float*)d_in[1];
    const float* w_gh = (const float*)d_in[2];
    const float* b_g  = (const float*)d_in[3];
    const float* w_ix = (const float*)d_in[4];
    const float* w_ih = (const float*)d_in[5];
    const float* b_i  = (const float*)d_in[6];
    const float* w_fx = (const float*)d_in[7];
    const float* w_fh = (const float*)d_in[8];
    const float* b_f  = (const float*)d_in[9];
    const float* w_ox = (const float*)d_in[10];
    const float* w_oh = (const float*)d_in[11];
    const float* b_o  = (const float*)d_in[12];
    const float* w_out = (const float*)d_in[13];
    const float* b_out = (const float*)d_in[14];
    float* out = (float*)d_out;

    char* ws = (char*)d_ws;
    size_t off = 0;
    auto alloc = [&](size_t bytes) { void* p = ws + off; off += (bytes + 255) & ~255ull; return p; };
    // flags (A+B, 32KB) | H0c contiguous -> one zeroing kernel
    unsigned*       flags = (unsigned*)alloc(32768);      // 2 x 256 WG-flags, 64B apart
    unsigned short* H0c   = (unsigned short*)alloc((size_t)Bdim * 512 * 2);
    unsigned short* H1c   = (unsigned short*)alloc((size_t)Bdim * 512 * 2);
    float*          Hf32  = (float*)alloc((size_t)Bdim * 512 * 4);
    unsigned short* Whi   = (unsigned short*)alloc(2048ull * Kpad * 2);
    unsigned short* Wlo   = (unsigned short*)alloc(2048ull * Kpad * 2);
    unsigned short* Xhi   = (unsigned short*)alloc((size_t)Tdim * Bdim * 32 * 2);
    unsigned short* Xlo   = (unsigned short*)alloc((size_t)Tdim * Bdim * 32 * 2);
    (void)ws_size; (void)in_sizes; (void)n_in; (void)out_size;

    k_prep_w<<<(2048 * Kpad + 255) / 256, 256, 0, stream>>>(
        w_gh, w_ih, w_fh, w_oh, w_gx, w_ix, w_fx, w_ox, Whi, Wlo);
    k_prep_x<<<(Tdim * Bdim * 32 + 255) / 256, 256, 0, stream>>>(x, Xhi, Xlo);
    // zero flags(32KB)+H0c(256KB): 294,912 B = 73,728 floats = 288 blocks
    k_zero<<<288, 256, 0, stream>>>((float*)flags);

    hipFuncSetAttribute((const void*)k_persist,
                        hipFuncAttributeMaxDynamicSharedMemorySize, LDS_BYTES);
    k_persist<<<dim3(256), dim3(256), LDS_BYTES, stream>>>(
        Whi, Wlo, Xhi, Xlo, H0c, H1c,
        Hf32, b_g, b_i, b_f, b_o, flags);

    k_out<<<256, 64, 0, stream>>>(Hf32, w_out, b_out, out);
}